// Round 2
// baseline (1201.218 us; speedup 1.0000x reference)
//
#include <hip/hip_runtime.h>

typedef __attribute__((ext_vector_type(8))) __bf16 bf16x8;
typedef __attribute__((ext_vector_type(4))) __bf16 bf16x4;
typedef __attribute__((ext_vector_type(4))) float f32x4;

#define SEQ   4096
#define NIN   1024
#define DH    128
#define NOUTD 1024
#define HEADS 8
#define CPH   1280   // cols per head in DOUT

// ---------------------------------------------------------------- f32 -> bf16
__global__ __launch_bounds__(256) void k_cvt(const float* __restrict__ src,
                                             __bf16* __restrict__ dst, int n) {
  int i = (blockIdx.x * 256 + threadIdx.x) * 4;
  if (i >= n) return;
  float4 v = *(const float4*)(src + i);
  bf16x4 o = { (__bf16)v.x, (__bf16)v.y, (__bf16)v.z, (__bf16)v.w };
  *(bf16x4*)(dst + i) = o;
}

// ---------------------------------------------------------------- zero d_out
__global__ __launch_bounds__(256) void k_zero(float4* __restrict__ p) {
  p[(size_t)blockIdx.x * 256 + threadIdx.x] = float4{0.f, 0.f, 0.f, 0.f};
}

// ------------------------------------------- GEMM: out = x @ W^T + b, scatter
// A = xb (M=4096 x K=1024), Bt = wb (N=10240 x K=1024), both row-major bf16.
// Epilogue: c<128 -> Kx[h][i][c] * 1/sqrt(128); c<256 -> Qx[h][i][c-128];
//           else  -> Vt[h][c-256][i]  (transposed V for PV-step Bt layout)
__global__ __launch_bounds__(256) void k_gemm_qkv(
    const __bf16* __restrict__ xb, const __bf16* __restrict__ wb,
    const float* __restrict__ bias,
    __bf16* __restrict__ Kx, __bf16* __restrict__ Qx, __bf16* __restrict__ Vt)
{
  __shared__ __bf16 As[128 * 32];
  __shared__ __bf16 Bs[128 * 32];
  const int tid = threadIdx.x;
  const int w = tid >> 6, l = tid & 63;
  const int i0 = blockIdx.x * 128;
  const int n0 = blockIdx.y * 128;
  const int lrow = l & 15;
  const int lkb  = (l >> 4) * 16;          // byte offset of k-chunk within 64B row
  const int soff = (w * 2) * 1024 + l * 16; // byte offset in 8KB tile, q=0

  f32x4 acc[4][4] = {};

  for (int kt = 0; kt < 32; ++kt) {
    __syncthreads();
#pragma unroll
    for (int q = 0; q < 2; ++q) {
      int off = soff + q * 1024;
      int row = off >> 6, kb = off & 63;
      const __bf16* ga = xb + (size_t)(i0 + row) * NIN + kt * 32 + (kb >> 1);
      const __bf16* gb = wb + (size_t)(n0 + row) * NIN + kt * 32 + (kb >> 1);
      __builtin_amdgcn_global_load_lds(
          (const __attribute__((address_space(1))) void*)ga,
          (__attribute__((address_space(3))) void*)((char*)As + (w * 2 + q) * 1024),
          16, 0, 0);
      __builtin_amdgcn_global_load_lds(
          (const __attribute__((address_space(1))) void*)gb,
          (__attribute__((address_space(3))) void*)((char*)Bs + (w * 2 + q) * 1024),
          16, 0, 0);
    }
    __syncthreads();
    bf16x8 af[4], bfr[4];
#pragma unroll
    for (int mi = 0; mi < 4; ++mi)
      af[mi] = *(const bf16x8*)((const char*)As + (((w >> 1) * 64 + mi * 16 + lrow) * 64) + lkb);
#pragma unroll
    for (int ni = 0; ni < 4; ++ni)
      bfr[ni] = *(const bf16x8*)((const char*)Bs + (((w & 1) * 64 + ni * 16 + lrow) * 64) + lkb);
#pragma unroll
    for (int mi = 0; mi < 4; ++mi)
#pragma unroll
      for (int ni = 0; ni < 4; ++ni)
        acc[mi][ni] = __builtin_amdgcn_mfma_f32_16x16x32_bf16(af[mi], bfr[ni], acc[mi][ni], 0, 0, 0);
  }

  // epilogue scatter
  const int iw = i0 + (w >> 1) * 64;
  const int nw = n0 + (w & 1) * 64;
  const int lhi = l >> 4;
#pragma unroll
  for (int ni = 0; ni < 4; ++ni) {
    int n = nw + ni * 16 + lrow;
    float bv = bias[n];
    int h = n / CPH;
    int c = n - h * CPH;
    if (c < 256) {
#pragma unroll
      for (int mi = 0; mi < 4; ++mi)
#pragma unroll
        for (int r = 0; r < 4; ++r) {
          int i = iw + mi * 16 + lhi * 4 + r;
          float v = acc[mi][ni][r] + bv;
          if (c < 128)
            Kx[(((size_t)h * SEQ + i) << 7) + c] = (__bf16)(v * 0.08838834764831845f);
          else
            Qx[(((size_t)h * SEQ + i) << 7) + (c - 128)] = (__bf16)v;
        }
    } else {
      int e = c - 256;
#pragma unroll
      for (int mi = 0; mi < 4; ++mi) {
        int ib = iw + mi * 16 + lhi * 4;
        bf16x4 pk = { (__bf16)(acc[mi][ni][0] + bv), (__bf16)(acc[mi][ni][1] + bv),
                      (__bf16)(acc[mi][ni][2] + bv), (__bf16)(acc[mi][ni][3] + bv) };
        *(bf16x4*)(Vt + (((size_t)h * NOUTD + e) << 12) + ib) = pk;
      }
    }
  }
}

// ------------------------------------------------- flash attention per (h,it)
// blockIdx = it*8 + h  (head -> XCD affinity). 8 waves, 512 threads.
// Wave w: S-phase strip (mhalf=w>>2 rows, nstrip=w&3 cols); PV e-slice w*128.
__global__ __launch_bounds__(512, 2) void k_attn(
    const __bf16* __restrict__ Kx, const __bf16* __restrict__ Qx,
    const __bf16* __restrict__ Vt, float* __restrict__ out)
{
  __shared__ __bf16 Klds[64 * 128];
  __shared__ __bf16 Qlds[64 * 128];
  __shared__ __bf16 Plds[64 * 64];
  __shared__ float s_tmax[4][64];
  __shared__ float s_tsum[4][64];
  __shared__ float s_m[64], s_l[64], s_scale[64];
  __shared__ int s_flag;

  const int tid = threadIdx.x;
  const int w = tid >> 6, l = tid & 63;
  const int bh = blockIdx.x & 7;
  const int it = blockIdx.x >> 3;
  const int i0 = it * 64;
  const int mhalf = w >> 2, nstrip = w & 3;
  const int l15 = l & 15, lhi = l >> 4;
  const float L2E = 1.44269504f;

  // stage K tile (64 x 128), swizzled
  {
    int row = tid >> 3;
    int cb = (tid & 7) * 32;
    const char* g = (const char*)(Kx + (((size_t)bh * SEQ + i0 + row) << 7)) + cb;
    int4 v0 = *(const int4*)g;
    int4 v1 = *(const int4*)(g + 16);
    int sw = (row & 7) << 4;
    *(int4*)((char*)Klds + ((row * 256 + cb) ^ sw)) = v0;
    *(int4*)((char*)Klds + ((row * 256 + cb + 16) ^ sw)) = v1;
  }
  if (tid < 64) { s_m[tid] = -1e30f; s_l[tid] = 0.f; }
  __syncthreads();

  // K fragments to registers (A-operand for S = K @ Q^T)
  bf16x8 kf[2][4];
#pragma unroll
  for (int mm = 0; mm < 2; ++mm)
#pragma unroll
    for (int ks = 0; ks < 4; ++ks) {
      int row = mhalf * 32 + mm * 16 + l15;
      int cbyte = (ks * 32 + lhi * 8) * 2;
      kf[mm][ks] = *(const bf16x8*)((const char*)Klds + ((row * 256 + cbyte) ^ ((row & 7) << 4)));
    }

  f32x4 o[4][8] = {};
  const __bf16* vp = Vt + (((size_t)bh * NOUTD + w * 128 + l15) << 12) + lhi * 8;

  for (int jt = 0; jt < 64; ++jt) {
    const int j0 = jt * 64;
    __syncthreads();  // A: prev PV done with Plds/Qlds
    {
      int row = tid >> 3;
      int cb = (tid & 7) * 32;
      const char* g = (const char*)(Qx + (((size_t)bh * SEQ + j0 + row) << 7)) + cb;
      int4 v0 = *(const int4*)g;
      int4 v1 = *(const int4*)(g + 16);
      int sw = (row & 7) << 4;
      *(int4*)((char*)Qlds + ((row * 256 + cb) ^ sw)) = v0;
      *(int4*)((char*)Qlds + ((row * 256 + cb + 16) ^ sw)) = v1;
    }
    __syncthreads();  // B: Q staged

    // S strip: rows mhalf*32..+32, cols nstrip*16..+16
    f32x4 s0 = {0.f, 0.f, 0.f, 0.f}, s1 = {0.f, 0.f, 0.f, 0.f};
#pragma unroll
    for (int ks = 0; ks < 4; ++ks) {
      int rowq = nstrip * 16 + l15;
      bf16x8 qf = *(const bf16x8*)((const char*)Qlds +
                   ((rowq * 256 + (ks * 32 + lhi * 8) * 2) ^ ((rowq & 7) << 4)));
      s0 = __builtin_amdgcn_mfma_f32_16x16x32_bf16(kf[0][ks], qf, s0, 0, 0, 0);
      s1 = __builtin_amdgcn_mfma_f32_16x16x32_bf16(kf[1][ks], qf, s1, 0, 0, 0);
    }

    // per-row strip max (reduce across 16 lanes = cols)
    float mx0[4], mx1[4];
#pragma unroll
    for (int r = 0; r < 4; ++r) { mx0[r] = s0[r]; mx1[r] = s1[r]; }
#pragma unroll
    for (int d = 1; d < 16; d <<= 1)
#pragma unroll
      for (int r = 0; r < 4; ++r) {
        mx0[r] = fmaxf(mx0[r], __shfl_xor(mx0[r], d));
        mx1[r] = fmaxf(mx1[r], __shfl_xor(mx1[r], d));
      }
    if (l15 == 0) {
#pragma unroll
      for (int r = 0; r < 4; ++r) {
        s_tmax[nstrip][mhalf * 32 + lhi * 4 + r] = mx0[r];
        s_tmax[nstrip][mhalf * 32 + 16 + lhi * 4 + r] = mx1[r];
      }
    }
    __syncthreads();  // C

    if (w == 0) {
      float pm = fmaxf(fmaxf(s_tmax[0][l], s_tmax[1][l]), fmaxf(s_tmax[2][l], s_tmax[3][l]));
      float mo = s_m[l];
      float mn = fmaxf(mo, pm);
      float sc = exp2f((mo - mn) * L2E);
      unsigned long long any = __ballot(mn > mo);
      if (l == 0) s_flag = (any != 0ull) ? 1 : 0;
      s_m[l] = mn;
      s_scale[l] = sc;
      s_l[l] *= sc;
    }
    __syncthreads();  // D: m/scale/flag ready

    // P = exp(S - m), strip sums, write Plds (bf16, swizzled)
#pragma unroll
    for (int mm = 0; mm < 2; ++mm) {
      f32x4& sv = mm ? s1 : s0;
      int rbase = mhalf * 32 + mm * 16 + lhi * 4;
      float p[4], t[4];
#pragma unroll
      for (int r = 0; r < 4; ++r) {
        p[r] = exp2f((sv[r] - s_m[rbase + r]) * L2E);
        t[r] = p[r];
      }
#pragma unroll
      for (int d = 1; d < 16; d <<= 1)
#pragma unroll
        for (int r = 0; r < 4; ++r) t[r] += __shfl_xor(t[r], d);
      if (l15 == 0)
#pragma unroll
        for (int r = 0; r < 4; ++r) s_tsum[nstrip][rbase + r] = t[r];
#pragma unroll
      for (int r = 0; r < 4; ++r) {
        int row = rbase + r;
        *(__bf16*)((char*)Plds + ((row * 128 + (nstrip * 16 + l15) * 2) ^ ((row & 7) << 4))) =
            (__bf16)p[r];
      }
    }
    __syncthreads();  // E: Plds + tsum ready

    if (w == 0)
      s_l[l] += s_tsum[0][l] + s_tsum[1][l] + s_tsum[2][l] + s_tsum[3][l];

    if (s_flag) {  // rare: running max increased
#pragma unroll
      for (int mi = 0; mi < 4; ++mi) {
        float sc[4];
#pragma unroll
        for (int r = 0; r < 4; ++r) sc[r] = s_scale[mi * 16 + lhi * 4 + r];
#pragma unroll
        for (int ni = 0; ni < 8; ++ni)
#pragma unroll
          for (int r = 0; r < 4; ++r) o[mi][ni][r] *= sc[r];
      }
    }

    // PV: O[64 x 128-slice] += P(64x64) @ V(64x128-slice)
#pragma unroll
    for (int ks = 0; ks < 2; ++ks) {
      bf16x8 ap[4];
#pragma unroll
      for (int mi = 0; mi < 4; ++mi) {
        int row = mi * 16 + l15;
        ap[mi] = *(const bf16x8*)((const char*)Plds +
                  ((row * 128 + (ks * 32 + lhi * 8) * 2) ^ ((row & 7) << 4)));
      }
#pragma unroll
      for (int ni = 0; ni < 8; ++ni) {
        bf16x8 bv = *(const bf16x8*)(vp + ((size_t)ni << 16) + j0 + ks * 32);
#pragma unroll
        for (int mi = 0; mi < 4; ++mi)
          o[mi][ni] = __builtin_amdgcn_mfma_f32_16x16x32_bf16(ap[mi], bv, o[mi][ni], 0, 0, 0);
      }
    }
  }

  __syncthreads();  // l_run final

#pragma unroll
  for (int mi = 0; mi < 4; ++mi) {
    float inv[4];
#pragma unroll
    for (int r = 0; r < 4; ++r) inv[r] = 1.0f / s_l[mi * 16 + lhi * 4 + r];
#pragma unroll
    for (int ni = 0; ni < 8; ++ni) {
      int e = w * 128 + ni * 16 + l15;
#pragma unroll
      for (int r = 0; r < 4; ++r) {
        int i = i0 + mi * 16 + lhi * 4 + r;
        atomicAdd(out + ((size_t)i << 10) + e, o[mi][ni][r] * inv[r]);
      }
    }
  }
}

// ---------------------------------------------------------------- LayerNorm
__global__ __launch_bounds__(256) void k_ln(float* __restrict__ io,
                                            const float* __restrict__ lw,
                                            const float* __restrict__ lb) {
  const int i = blockIdx.x, t = threadIdx.x;
  const int w = t >> 6, l = t & 63;
  float4 v = *(const float4*)(io + ((size_t)i << 10) + t * 4);
  float s = v.x + v.y + v.z + v.w;
  float q = v.x * v.x + v.y * v.y + v.z * v.z + v.w * v.w;
#pragma unroll
  for (int d = 1; d < 64; d <<= 1) {
    s += __shfl_xor(s, d);
    q += __shfl_xor(q, d);
  }
  __shared__ float red[4][2];
  if (l == 0) { red[w][0] = s; red[w][1] = q; }
  __syncthreads();
  s = red[0][0] + red[1][0] + red[2][0] + red[3][0];
  q = red[0][1] + red[1][1] + red[2][1] + red[3][1];
  float mean = s * (1.0f / 1024.0f);
  float var = q * (1.0f / 1024.0f) - mean * mean;
  float rstd = rsqrtf(var + 1e-5f);
  float4 gw = *(const float4*)(lw + t * 4);
  float4 gb = *(const float4*)(lb + t * 4);
  float4 ov;
  ov.x = (v.x - mean) * rstd * gw.x + gb.x;
  ov.y = (v.y - mean) * rstd * gw.y + gb.y;
  ov.z = (v.z - mean) * rstd * gw.z + gb.z;
  ov.w = (v.w - mean) * rstd * gw.w + gb.w;
  *(float4*)(io + ((size_t)i << 10) + t * 4) = ov;
}

// ---------------------------------------------------------------- launch
extern "C" void kernel_launch(void* const* d_in, const int* in_sizes, int n_in,
                              void* d_out, int out_size, void* d_ws, size_t ws_size,
                              hipStream_t stream) {
  (void)in_sizes; (void)n_in; (void)out_size; (void)ws_size;
  const float* x  = (const float*)d_in[0];
  const float* W  = (const float*)d_in[1];
  const float* b  = (const float*)d_in[2];
  const float* lw = (const float*)d_in[3];
  const float* lb = (const float*)d_in[4];
  float* out = (float*)d_out;
  char* ws = (char*)d_ws;

  __bf16* xb = (__bf16*)ws;                                    //  8 MB
  __bf16* wb = (__bf16*)(ws + (size_t)8  * 1024 * 1024);       // 20 MB
  __bf16* Kx = (__bf16*)(ws + (size_t)28 * 1024 * 1024);       //  8 MB
  __bf16* Qx = (__bf16*)(ws + (size_t)36 * 1024 * 1024);       //  8 MB
  __bf16* Vt = (__bf16*)(ws + (size_t)44 * 1024 * 1024);       // 64 MB -> 108 MB total

  k_cvt<<<4096, 256, 0, stream>>>(x, xb, SEQ * NIN);
  k_cvt<<<10240, 256, 0, stream>>>(W, wb, HEADS * CPH * NIN);
  k_gemm_qkv<<<dim3(32, 80), 256, 0, stream>>>(xb, wb, b, Kx, Qx, Vt);
  k_zero<<<4096, 256, 0, stream>>>((float4*)out);
  k_attn<<<512, 512, 0, stream>>>(Kx, Qx, Vt, out);
  k_ln<<<4096, 256, 0, stream>>>(out, lw, lb);
}

// Round 3
// 831.317 us; speedup vs baseline: 1.4450x; 1.4450x over previous
//
#include <hip/hip_runtime.h>

typedef __attribute__((ext_vector_type(8))) __bf16 bf16x8;
typedef __attribute__((ext_vector_type(4))) __bf16 bf16x4;
typedef __attribute__((ext_vector_type(4))) float f32x4;
typedef __attribute__((ext_vector_type(16))) float f32x16;

#define SEQ   4096
#define NIN   1024
#define DH    128
#define NOUTD 1024
#define HEADS 8
#define CPH   1280
#define L2E   1.44269504f

static __device__ inline f32x16 zero16() {
  f32x16 z;
#pragma unroll
  for (int r = 0; r < 16; ++r) z[r] = 0.f;
  return z;
}

static __device__ inline unsigned pk2(float a, float b) {
  unsigned short ua = __builtin_bit_cast(unsigned short, (__bf16)a);
  unsigned short ub = __builtin_bit_cast(unsigned short, (__bf16)b);
  return (unsigned)ua | ((unsigned)ub << 16);
}

// ---------------------------------------------------------------- f32 -> bf16
__global__ __launch_bounds__(256) void k_cvt(const float* __restrict__ src,
                                             __bf16* __restrict__ dst, int n) {
  int i = (blockIdx.x * 256 + threadIdx.x) * 4;
  if (i >= n) return;
  float4 v = *(const float4*)(src + i);
  bf16x4 o = { (__bf16)v.x, (__bf16)v.y, (__bf16)v.z, (__bf16)v.w };
  *(bf16x4*)(dst + i) = o;
}

// ---------------------------------------------------------------- zero d_out
__global__ __launch_bounds__(256) void k_zero(float4* __restrict__ p) {
  p[(size_t)blockIdx.x * 256 + threadIdx.x] = float4{0.f, 0.f, 0.f, 0.f};
}

// ------------------------------------------- GEMM: out = x @ W^T + b, scatter
__global__ __launch_bounds__(256) void k_gemm_qkv(
    const __bf16* __restrict__ xb, const __bf16* __restrict__ wb,
    const float* __restrict__ bias,
    __bf16* __restrict__ Kx, __bf16* __restrict__ Qx, __bf16* __restrict__ Vt)
{
  __shared__ __align__(16) __bf16 As[128 * 32];
  __shared__ __align__(16) __bf16 Bs[128 * 32];
  const int tid = threadIdx.x;
  const int w = tid >> 6, l = tid & 63;
  const int i0 = blockIdx.x * 128;
  const int n0 = blockIdx.y * 128;
  const int lrow = l & 15;
  const int lkb  = (l >> 4) * 16;
  const int soff = (w * 2) * 1024 + l * 16;

  f32x4 acc[4][4] = {};

  for (int kt = 0; kt < 32; ++kt) {
    __syncthreads();
#pragma unroll
    for (int q = 0; q < 2; ++q) {
      int off = soff + q * 1024;
      int row = off >> 6, kb = off & 63;
      const __bf16* ga = xb + (size_t)(i0 + row) * NIN + kt * 32 + (kb >> 1);
      const __bf16* gb = wb + (size_t)(n0 + row) * NIN + kt * 32 + (kb >> 1);
      __builtin_amdgcn_global_load_lds(
          (const __attribute__((address_space(1))) void*)ga,
          (__attribute__((address_space(3))) void*)((char*)As + (w * 2 + q) * 1024),
          16, 0, 0);
      __builtin_amdgcn_global_load_lds(
          (const __attribute__((address_space(1))) void*)gb,
          (__attribute__((address_space(3))) void*)((char*)Bs + (w * 2 + q) * 1024),
          16, 0, 0);
    }
    __syncthreads();
    bf16x8 af[4], bfr[4];
#pragma unroll
    for (int mi = 0; mi < 4; ++mi)
      af[mi] = *(const bf16x8*)((const char*)As + (((w >> 1) * 64 + mi * 16 + lrow) * 64) + lkb);
#pragma unroll
    for (int ni = 0; ni < 4; ++ni)
      bfr[ni] = *(const bf16x8*)((const char*)Bs + (((w & 1) * 64 + ni * 16 + lrow) * 64) + lkb);
#pragma unroll
    for (int mi = 0; mi < 4; ++mi)
#pragma unroll
      for (int ni = 0; ni < 4; ++ni)
        acc[mi][ni] = __builtin_amdgcn_mfma_f32_16x16x32_bf16(af[mi], bfr[ni], acc[mi][ni], 0, 0, 0);
  }

  const int iw = i0 + (w >> 1) * 64;
  const int nw = n0 + (w & 1) * 64;
  const int lhi = l >> 4;
#pragma unroll
  for (int ni = 0; ni < 4; ++ni) {
    int n = nw + ni * 16 + lrow;
    float bv = bias[n];
    int h = n / CPH;
    int c = n - h * CPH;
    if (c < 256) {
#pragma unroll
      for (int mi = 0; mi < 4; ++mi)
#pragma unroll
        for (int r = 0; r < 4; ++r) {
          int i = iw + mi * 16 + lhi * 4 + r;
          float v = acc[mi][ni][r] + bv;
          if (c < 128)
            Kx[(((size_t)h * SEQ + i) << 7) + c] = (__bf16)(v * 0.08838834764831845f);
          else
            Qx[(((size_t)h * SEQ + i) << 7) + (c - 128)] = (__bf16)v;
        }
    } else {
      int e = c - 256;
#pragma unroll
      for (int mi = 0; mi < 4; ++mi) {
        int ib = iw + mi * 16 + lhi * 4;
        bf16x4 pk = { (__bf16)(acc[mi][ni][0] + bv), (__bf16)(acc[mi][ni][1] + bv),
                      (__bf16)(acc[mi][ni][2] + bv), (__bf16)(acc[mi][ni][3] + bv) };
        *(bf16x4*)(Vt + (((size_t)h * NOUTD + e) << 12) + ib) = pk;
      }
    }
  }
}

// --------------------------------------------------------- staging helpers
// Q tile: 64 rows x 128 d (256B rows, 16 chunks of 16B), XOR-swizzle (row&15)<<4
static __device__ inline void stage_q(const __bf16* Qh, char* dst, int j0,
                                      int tid, int nthr) {
#pragma unroll
  for (int s = tid; s < 1024; s += nthr) {
    int row = s >> 4, ch = s & 15;
    const char* src = (const char*)Qh + (((size_t)(j0 + row)) << 8) +
                      ((ch << 4) ^ ((row & 15) << 4));
    __builtin_amdgcn_global_load_lds(
        (const __attribute__((address_space(1))) void*)src,
        (__attribute__((address_space(3))) void*)(dst + (s << 4)), 16, 0, 0);
  }
}

// V tile: 256 e-rows x 64 j (128B rows, 8 chunks of 16B), XOR-swizzle (row&7)<<4
static __device__ inline void stage_v(const char* Vhb, char* dst, int j0,
                                      int tid) {
#pragma unroll
  for (int s = tid; s < 2048; s += 512) {
    int row = s >> 3, ch = s & 7;
    const char* src = Vhb + ((size_t)row << 13) + ((size_t)j0 << 1) +
                      ((ch << 4) ^ ((row & 7) << 4));
    __builtin_amdgcn_global_load_lds(
        (const __attribute__((address_space(1))) void*)src,
        (__attribute__((address_space(3))) void*)(dst + (s << 4)), 16, 0, 0);
  }
}

// --------------------------------------------------------- pass A: softmax stats
// grid 256 = h(8) x itile(32 of 128 rows). 256 thr, 4 waves x 32 i-rows.
// S^T = mfma(Q_frag, K_frag): i = lane&31 (lane-local) -> per-lane online m/l.
__global__ __launch_bounds__(256) void k_stats(
    const __bf16* __restrict__ Kx, const __bf16* __restrict__ Qx,
    float* __restrict__ stat_m, float* __restrict__ stat_il)
{
  __shared__ __align__(16) char Qb[2][16384];
  const int tid = threadIdx.x;
  const int w = tid >> 6, l = tid & 63;
  const int l31 = l & 31, hl = l >> 5;
  const int b = blockIdx.x;
  const int h = b >> 5;
  const int i_base = (b & 31) * 128;
  const __bf16* Kh = Kx + ((size_t)h * SEQ << 7);
  const __bf16* Qh = Qx + ((size_t)h * SEQ << 7);

  bf16x8 kf[8];
#pragma unroll
  for (int c = 0; c < 8; ++c)
    kf[c] = *(const bf16x8*)(Kh + (((size_t)(i_base + 32 * w + l31)) << 7) + c * 16 + hl * 8);

  float m_run = -1e30f, l_run = 0.f;

  stage_q(Qh, Qb[0], 0, tid, 256);
  __syncthreads();

  for (int jt = 0; jt < 64; ++jt) {
    const int cur = jt & 1;
    if (jt < 63) stage_q(Qh, Qb[cur ^ 1], (jt + 1) * 64, tid, 256);
    const char* qb = Qb[cur];

    f32x16 s0 = zero16(), s1 = zero16();
#pragma unroll
    for (int c = 0; c < 8; ++c) {
      int cb = ((2 * c + hl) << 4);
      bf16x8 a0 = *(const bf16x8*)(qb + (l31 << 8) + (cb ^ ((l31 & 15) << 4)));
      bf16x8 a1 = *(const bf16x8*)(qb + ((32 + l31) << 8) + (cb ^ ((l31 & 15) << 4)));
      s0 = __builtin_amdgcn_mfma_f32_32x32x16_bf16(a0, kf[c], s0, 0, 0, 0);
      s1 = __builtin_amdgcn_mfma_f32_32x32x16_bf16(a1, kf[c], s1, 0, 0, 0);
    }

    float pm = -1e30f;
#pragma unroll
    for (int r = 0; r < 16; ++r) pm = fmaxf(pm, fmaxf(s0[r], s1[r]));
    float mn = fmaxf(m_run, pm);
    l_run *= exp2f((m_run - mn) * L2E);
    float a = 0.f;
#pragma unroll
    for (int r = 0; r < 16; ++r)
      a += exp2f((s0[r] - mn) * L2E) + exp2f((s1[r] - mn) * L2E);
    l_run += a;
    m_run = mn;
    __syncthreads();
  }

  float mp = __shfl_xor(m_run, 32);
  float lp = __shfl_xor(l_run, 32);
  float mf = fmaxf(m_run, mp);
  float lf = l_run * exp2f((m_run - mf) * L2E) + lp * exp2f((mp - mf) * L2E);
  if (hl == 0) {
    int i = i_base + 32 * w + l31;
    stat_m[h * SEQ + i] = mf;
    stat_il[h * SEQ + i] = 1.0f / lf;
  }
}

// --------------------------------------------------------- pass B: P*V with stats
// grid 512 = (h, it 16 x 256 i, et 4 x 256 e); 512 thr, 8 waves x 32 i-rows.
// blockIdx = (g&7) + 8*((g>>3)*16 + it), g = h*4+et  -> XCD-affine V panels.
__global__ __launch_bounds__(512, 2) void k_attn2(
    const __bf16* __restrict__ Kx, const __bf16* __restrict__ Qx,
    const __bf16* __restrict__ Vt, const float* __restrict__ stat_m,
    const float* __restrict__ stat_il, float* __restrict__ out)
{
  __shared__ __align__(16) char Qb[2][16384];
  __shared__ __align__(16) char Vb[2][32768];
  __shared__ float s_linv[256];

  const int tid = threadIdx.x;
  const int w = tid >> 6, l = tid & 63;
  const int l31 = l & 31, hl = l >> 5;

  const int b = blockIdx.x;
  const int gLow = b & 7, inner = b >> 3;
  const int g = (inner >> 4) * 8 + gLow;
  const int it = inner & 15;
  const int h = g >> 2, et = g & 3;
  const int i_base = it * 256, e_base = et * 256;

  const __bf16* Kh = Kx + ((size_t)h * SEQ << 7);
  const __bf16* Qh = Qx + ((size_t)h * SEQ << 7);
  const char* Vhb = (const char*)Vt + (((size_t)(h * NOUTD + e_base)) << 13);

  if (tid < 256) s_linv[tid] = stat_il[h * SEQ + i_base + tid];
  const float m_i = stat_m[h * SEQ + i_base + 32 * w + l31];

  // K fragments resident: B-operand, lane: K[i_base+32w+l31][16c + 8hl + e]
  bf16x8 kf[8];
#pragma unroll
  for (int c = 0; c < 8; ++c)
    kf[c] = *(const bf16x8*)(Kh + (((size_t)(i_base + 32 * w + l31)) << 7) + c * 16 + hl * 8);

  f32x16 acc[8];
#pragma unroll
  for (int n = 0; n < 8; ++n) acc[n] = zero16();

  stage_q(Qh, Qb[0], 0, tid, 512);
  stage_v(Vhb, Vb[0], 0, tid);
  __syncthreads();

  for (int jt = 0; jt < 64; ++jt) {
    const int cur = jt & 1;
    const int j0n = (jt + 1) * 64;
    if (jt < 63) {
      stage_q(Qh, Qb[cur ^ 1], j0n, tid, 512);
      stage_v(Vhb, Vb[cur ^ 1], j0n, tid);
    }
    const char* qb = Qb[cur];
    const char* vb = Vb[cur];

    // S^T: rows j (2 M-tiles of 32), cols i = lane&31
    f32x16 s0 = zero16(), s1 = zero16();
#pragma unroll
    for (int c = 0; c < 8; ++c) {
      int cb = ((2 * c + hl) << 4);
      bf16x8 a0 = *(const bf16x8*)(qb + (l31 << 8) + (cb ^ ((l31 & 15) << 4)));
      bf16x8 a1 = *(const bf16x8*)(qb + ((32 + l31) << 8) + (cb ^ ((l31 & 15) << 4)));
      s0 = __builtin_amdgcn_mfma_f32_32x32x16_bf16(a0, kf[c], s0, 0, 0, 0);
      s1 = __builtin_amdgcn_mfma_f32_32x32x16_bf16(a1, kf[c], s1, 0, 0, 0);
    }

    // P = exp(S - m), reconstruct PV A-frags in-register (one shfl_xor(32))
    bf16x8 pf[4];
#pragma unroll
    for (int c2 = 0; c2 < 4; ++c2) {
      const f32x16& sv = (c2 >> 1) ? s1 : s0;
      const int base = (c2 & 1) * 8;
      float e0 = exp2f((sv[base + 0] - m_i) * L2E);
      float e1 = exp2f((sv[base + 1] - m_i) * L2E);
      float e2 = exp2f((sv[base + 2] - m_i) * L2E);
      float e3 = exp2f((sv[base + 3] - m_i) * L2E);
      float e4 = exp2f((sv[base + 4] - m_i) * L2E);
      float e5 = exp2f((sv[base + 5] - m_i) * L2E);
      float e6 = exp2f((sv[base + 6] - m_i) * L2E);
      float e7 = exp2f((sv[base + 7] - m_i) * L2E);
      unsigned WA0 = pk2(e0, e1), WA1 = pk2(e2, e3);
      unsigned WB0 = pk2(e4, e5), WB1 = pk2(e6, e7);
      unsigned send0 = hl ? WA0 : WB0;
      unsigned send1 = hl ? WA1 : WB1;
      unsigned r0 = (unsigned)__shfl_xor((int)send0, 32);
      unsigned r1 = (unsigned)__shfl_xor((int)send1, 32);
      int4 qd;
      qd.x = (int)(hl ? r0 : WA0);
      qd.y = (int)(hl ? r1 : WA1);
      qd.z = (int)(hl ? WB0 : r0);
      qd.w = (int)(hl ? WB1 : r1);
      pf[c2] = __builtin_bit_cast(bf16x8, qd);
    }

    // PV: acc[n] += P(32x64) @ V(64 x 32e), V from LDS
#pragma unroll
    for (int n = 0; n < 8; ++n) {
      const int erow = 32 * n + l31;
      const char* vrow = vb + (erow << 7);
      const int sw = (erow & 7) << 4;
#pragma unroll
      for (int c2 = 0; c2 < 4; ++c2) {
        bf16x8 bv = *(const bf16x8*)(vrow + ((((2 * c2 + hl) << 4)) ^ sw));
        acc[n] = __builtin_amdgcn_mfma_f32_32x32x16_bf16(pf[c2], bv, acc[n], 0, 0, 0);
      }
    }
    __syncthreads();
  }

  // epilogue: normalize + atomicAdd (cross-head accumulation)
#pragma unroll
  for (int n = 0; n < 8; ++n) {
    const int e = e_base + 32 * n + l31;
#pragma unroll
    for (int r = 0; r < 16; ++r) {
      int iloc = 32 * w + (r & 3) + 8 * (r >> 2) + 4 * hl;
      float v = acc[n][r] * s_linv[iloc];
      atomicAdd(out + (((size_t)(i_base + iloc)) << 10) + e, v);
    }
  }
}

// ---------------------------------------------------------------- LayerNorm
__global__ __launch_bounds__(256) void k_ln(float* __restrict__ io,
                                            const float* __restrict__ lw,
                                            const float* __restrict__ lb) {
  const int i = blockIdx.x, t = threadIdx.x;
  const int w = t >> 6, l = t & 63;
  float4 v = *(const float4*)(io + ((size_t)i << 10) + t * 4);
  float s = v.x + v.y + v.z + v.w;
  float q = v.x * v.x + v.y * v.y + v.z * v.z + v.w * v.w;
#pragma unroll
  for (int d = 1; d < 64; d <<= 1) {
    s += __shfl_xor(s, d);
    q += __shfl_xor(q, d);
  }
  __shared__ float red[4][2];
  if (l == 0) { red[w][0] = s; red[w][1] = q; }
  __syncthreads();
  s = red[0][0] + red[1][0] + red[2][0] + red[3][0];
  q = red[0][1] + red[1][1] + red[2][1] + red[3][1];
  float mean = s * (1.0f / 1024.0f);
  float var = q * (1.0f / 1024.0f) - mean * mean;
  float rstd = rsqrtf(var + 1e-5f);
  float4 gw = *(const float4*)(lw + t * 4);
  float4 gb = *(const float4*)(lb + t * 4);
  float4 ov;
  ov.x = (v.x - mean) * rstd * gw.x + gb.x;
  ov.y = (v.y - mean) * rstd * gw.y + gb.y;
  ov.z = (v.z - mean) * rstd * gw.z + gb.z;
  ov.w = (v.w - mean) * rstd * gw.w + gb.w;
  *(float4*)(io + ((size_t)i << 10) + t * 4) = ov;
}

// ---------------------------------------------------------------- launch
extern "C" void kernel_launch(void* const* d_in, const int* in_sizes, int n_in,
                              void* d_out, int out_size, void* d_ws, size_t ws_size,
                              hipStream_t stream) {
  (void)in_sizes; (void)n_in; (void)out_size; (void)ws_size;
  const float* x  = (const float*)d_in[0];
  const float* W  = (const float*)d_in[1];
  const float* b  = (const float*)d_in[2];
  const float* lw = (const float*)d_in[3];
  const float* lb = (const float*)d_in[4];
  float* out = (float*)d_out;
  char* ws = (char*)d_ws;

  __bf16* xb = (__bf16*)ws;                                    //  8 MB (dead after GEMM)
  __bf16* wb = (__bf16*)(ws + (size_t)8  * 1024 * 1024);       // 20 MB
  __bf16* Kx = (__bf16*)(ws + (size_t)28 * 1024 * 1024);       //  8 MB
  __bf16* Qx = (__bf16*)(ws + (size_t)36 * 1024 * 1024);       //  8 MB
  __bf16* Vt = (__bf16*)(ws + (size_t)44 * 1024 * 1024);       // 64 MB -> 108 MB total
  // stats reuse the (dead) xb region after the GEMM
  float* stat_m  = (float*)ws;                                 // 128 KB
  float* stat_il = (float*)(ws + (size_t)128 * 1024);          // 128 KB

  k_cvt<<<4096, 256, 0, stream>>>(x, xb, SEQ * NIN);
  k_cvt<<<10240, 256, 0, stream>>>(W, wb, HEADS * CPH * NIN);
  k_gemm_qkv<<<dim3(32, 80), 256, 0, stream>>>(xb, wb, b, Kx, Qx, Vt);
  k_zero<<<4096, 256, 0, stream>>>((float4*)out);
  k_stats<<<256, 256, 0, stream>>>(Kx, Qx, stat_m, stat_il);
  k_attn2<<<512, 512, 0, stream>>>(Kx, Qx, Vt, stat_m, stat_il, out);
  k_ln<<<4096, 256, 0, stream>>>(out, lw, lb);
}